// Round 4
// baseline (1052.863 us; speedup 1.0000x reference)
//
#include <hip/hip_runtime.h>

#define CC   256
#define HWS  4096
#define MPAD 4160   // 65*64, rows >= 4097 zero-padded
#define NB   4

typedef __attribute__((ext_vector_type(8))) short   short8;
typedef __attribute__((ext_vector_type(4))) float   floatx4;

static __device__ __forceinline__ short8 ld8(const unsigned short* p) {
  return *(const short8*)p;
}
static __device__ __forceinline__ unsigned short f2b(float x) {
  union { float f; unsigned u; } v; v.f = x;
  unsigned r = v.u + 0x7FFFu + ((v.u >> 16) & 1u);
  return (unsigned short)(r >> 16);
}

// ---- St[d][c] = sim[c][d] (bf16), Vw[d][c] = v_w[d][c] (bf16)
__global__ void prep_mats(const float* __restrict__ sim, const float* __restrict__ vw,
                          unsigned short* __restrict__ St, unsigned short* __restrict__ Vw) {
  int dd = blockIdx.x, c = threadIdx.x;
  St[dd*CC + c] = f2b(sim[c*CC + dd]);
  Vw[dd*CC + c] = f2b(vw[dd*CC + c]);
}

// ---- Kt[b][m][d] = bf16(concat[b][d][m]); m==4096 -> 1.2*exe; m>4096 -> 0
__global__ void build_kt(const float* __restrict__ img, const float* __restrict__ exe,
                         unsigned short* __restrict__ Kt) {
  int b = blockIdx.x, mt = blockIdx.y, dt = blockIdx.z;
  int tid = threadIdx.x;
  int m0 = mt*64, d0 = dt*64;
  if (mt == 64) {
    for (int i = 0; i < 16; ++i) {
      int m = m0 + (tid>>6) + i*4;
      int d = d0 + (tid&63);
      unsigned short v = 0;
      if (m == 4096) v = f2b(1.2f * exe[b*CC + d]);
      Kt[((size_t)b*MPAD + m)*CC + d] = v;
    }
    return;
  }
  __shared__ float tile[64][65];
  for (int i = 0; i < 16; ++i) {
    int dl = (tid>>6) + i*4, ml = tid&63;
    tile[dl][ml] = img[((size_t)b*CC + d0+dl)*HWS + m0+ml];
  }
  __syncthreads();
  for (int i = 0; i < 16; ++i) {
    int ml = (tid>>6) + i*4, dl = tid&63;
    Kt[((size_t)b*MPAD + m0+ml)*CC + d0+dl] = f2b(tile[dl][ml]);
  }
}

// ---- mode 0: T[b][n][d] = bf16( sum_c Kt[n][c]*St[d][c] )           (rows < HWS)
// ---- mode 1: Vbt[b][d][m] = bf16( sum_c Kt[m][c]*Vw[d][c] )         (rows < MPAD)
__global__ __launch_bounds__(256) void gemm_small(const unsigned short* __restrict__ Kt,
    const unsigned short* __restrict__ Bm, unsigned short* __restrict__ Tout,
    unsigned short* __restrict__ Vbt, int mode) {
  int b  = blockIdx.x;
  int r0 = blockIdx.y*64 + (threadIdx.x>>6)*16;
  int c0 = blockIdx.z*64;
  int lane = threadIdx.x & 63;
  int lo = lane & 15, hi = lane >> 4;
  floatx4 acc[4] = {};
  const unsigned short* arow = Kt + ((size_t)b*MPAD + r0 + lo)*CC + hi*8;
#pragma unroll
  for (int k = 0; k < 8; ++k) {
    short8 af = ld8(arow + k*32);
#pragma unroll
    for (int t = 0; t < 4; ++t) {
      short8 bf = ld8(Bm + (size_t)(c0 + t*16 + lo)*CC + k*32 + hi*8);
      acc[t] = __builtin_amdgcn_mfma_f32_16x16x32_bf16(af, bf, acc[t], 0, 0, 0);
    }
  }
  if (mode == 0) {
#pragma unroll
    for (int t = 0; t < 4; ++t)
#pragma unroll
      for (int r = 0; r < 4; ++r) {
        int n = r0 + hi*4 + r, dd = c0 + t*16 + lo;
        Tout[((size_t)b*HWS + n)*CC + dd] = f2b(acc[t][r]);
      }
  } else {
#pragma unroll
    for (int t = 0; t < 4; ++t)
#pragma unroll
      for (int r = 0; r < 4; ++r) {
        int m = r0 + hi*4 + r, dd = c0 + t*16 + lo;
        Vbt[((size_t)b*CC + dd)*MPAD + m] = f2b(acc[t][r]);
      }
  }
}

// ---- score mimicry of np/BLAS fp32 T-path, sequential FMA everywhere:
//  T32[n,d]  = seqFMA_{c=0..255}( U[c,n]*S[c,d] )           fp32
//  score[n]  = seqFMA_{d=0..255}( T32[n,d]*fl32(1.2f*exe[d]) ) fp32
// grid (NB, 256), block 256 (thread = d)
__global__ __launch_bounds__(256) void scores_kernel(const float* __restrict__ img,
    const float* __restrict__ sim, const float* __restrict__ exe,
    float* __restrict__ score32) {
  int b = blockIdx.x, n0 = blockIdx.y*16;
  int d = threadIdx.x;
  __shared__ float U[16][257];        // U[nl][c] = img[b, c, n0+nl]
  __shared__ float R[16][256];        // T32[nl][d]
  __shared__ float E[256];
  for (int idx = threadIdx.x; idx < 16*256; idx += 256) {
    int nl = idx & 15, c = idx >> 4;
    U[nl][c] = img[((size_t)b*CC + c)*HWS + n0 + nl];
  }
  E[d] = 1.2f * exe[b*CC + d];
  __syncthreads();
  float acc[16];
#pragma unroll
  for (int nl = 0; nl < 16; ++nl) acc[nl] = 0.f;
  for (int c = 0; c < CC; ++c) {
    float s_cd = sim[c*CC + d];
#pragma unroll
    for (int nl = 0; nl < 16; ++nl) acc[nl] = fmaf(U[nl][c], s_cd, acc[nl]);
  }
#pragma unroll
  for (int nl = 0; nl < 16; ++nl) R[nl][d] = acc[nl];
  __syncthreads();
  if (d < 16) {
    float s = 0.f;
    for (int dd = 0; dd < CC; ++dd) s = fmaf(R[d][dd], E[dd], s);
    score32[b*HWS + n0 + d] = s;
  }
}

// ---- local-max penalty + iterative top-150 (value desc, index asc), fp32 as reference
__global__ __launch_bounds__(256) void select_kernel(const float* __restrict__ scores,
                                                     int* __restrict__ qids) {
  int b = blockIdx.x, tid = threadIdx.x;
  __shared__ float sc[HWS];
  __shared__ float rv[4];
  __shared__ int   ri[4];
  for (int i = 0; i < 16; ++i) sc[tid + i*256] = scores[b*HWS + tid + i*256];
  __syncthreads();
  float pv[16];
  for (int i = 0; i < 16; ++i) {
    int idx = tid + i*256;
    int y = idx >> 6, x = idx & 63;
    float c0 = sc[idx];
    float v = c0;
    if (y >= 1 && y <= 62 && x >= 1 && x <= 62) {
      bool ismax = (c0 > sc[idx-64]) && (c0 >= sc[idx+64]) &&
                   (c0 > sc[idx-1])  && (c0 >= sc[idx+1]);
      if (!ismax) v = c0 - 1e9f;     // fp32, as reference (simil - NEG)
    }
    pv[i] = v;
  }
  __syncthreads();
  for (int i = 0; i < 16; ++i) sc[tid + i*256] = pv[i];
  __syncthreads();
  for (int q = 0; q < 150; ++q) {
    float bv = -3.0e38f; int bi = 0;
    for (int i = 0; i < 16; ++i) {
      int idx = tid + i*256; float v = sc[idx];
      if (v > bv || (v == bv && idx < bi)) { bv = v; bi = idx; }
    }
#pragma unroll
    for (int off = 32; off >= 1; off >>= 1) {
      float ov = __shfl_xor(bv, off);
      int   oi = __shfl_xor(bi, off);
      if (ov > bv || (ov == bv && oi < bi)) { bv = ov; bi = oi; }
    }
    int w = tid >> 6;
    if ((tid & 63) == 0) { rv[w] = bv; ri[w] = bi; }
    __syncthreads();
    if (tid == 0) {
      float bb = rv[0]; int ii = ri[0];
      for (int w2 = 1; w2 < 4; ++w2)
        if (rv[w2] > bb || (rv[w2] == bb && ri[w2] < ii)) { bb = rv[w2]; ii = ri[w2]; }
      qids[b*150 + q] = ii;
      sc[ii] = -3.0e38f;
    }
    __syncthreads();
  }
}

// ---- fused flash attention: 1 wave per block, 16 Q-rows, m-tiles of 64
__global__ __launch_bounds__(64) void flash_kernel(
    const unsigned short* __restrict__ Tb, const unsigned short* __restrict__ Kt,
    const unsigned short* __restrict__ Vbt, const float* __restrict__ mask,
    const float* __restrict__ img, float* __restrict__ out0) {
  int blk = blockIdx.x;
  int b = blk >> 8;
  int n0 = (blk & 255) << 4;
  int lane = threadIdx.x;
  int lo = lane & 15, hi = lane >> 4;
  __shared__ unsigned short plds[16*72];   // P transform buffer, stride 72 (16B-aligned rows)

  short8 q[8];
  const unsigned short* tb = Tb + ((size_t)b*HWS + n0 + lo)*CC + hi*8;
#pragma unroll
  for (int k = 0; k < 8; ++k) q[k] = ld8(tb + k*32);

  const float* mk = mask + b*HWS;
  float qmr[4];
#pragma unroll
  for (int r = 0; r < 4; ++r) qmr[r] = mk[n0 + hi*4 + r];

  float mrun[4], lrun[4];
#pragma unroll
  for (int r = 0; r < 4; ++r) { mrun[r] = -1e30f; lrun[r] = 0.f; }
  floatx4 o[16] = {};

  const unsigned short* ktb = Kt  + (size_t)b*MPAD*CC;
  const unsigned short* vtb = Vbt + (size_t)b*CC*MPAD;

  for (int mt = 0; mt < 65; ++mt) {
    int m0 = mt*64;
    floatx4 s[4] = {};
#pragma unroll
    for (int k = 0; k < 8; ++k) {
#pragma unroll
      for (int t = 0; t < 4; ++t) {
        short8 kb = ld8(ktb + (size_t)(m0 + t*16 + lo)*CC + k*32 + hi*8);
        s[t] = __builtin_amdgcn_mfma_f32_16x16x32_bf16(q[k], kb, s[t], 0, 0, 0);
      }
    }
    float sv[4][4];
#pragma unroll
    for (int t = 0; t < 4; ++t) {
      int m = m0 + t*16 + lo;
      float km = (m < HWS) ? mk[m] : 1.0f;
      bool pad = (m > HWS);              // m==4096 is exe column (never masked)
#pragma unroll
      for (int r = 0; r < 4; ++r) {
        float v = s[t][r];
        if (m < HWS && qmr[r]*km != 1.0f) v -= 1e9f;
        if (pad) v = -3.0e38f;
        sv[t][r] = v;
      }
    }
    float mnew[4], alpha[4];
#pragma unroll
    for (int r = 0; r < 4; ++r) {
      float v = fmaxf(fmaxf(sv[0][r], sv[1][r]), fmaxf(sv[2][r], sv[3][r]));
#pragma unroll
      for (int off = 1; off < 16; off <<= 1) v = fmaxf(v, __shfl_xor(v, off));
      mnew[r]  = fmaxf(mrun[r], v);
      alpha[r] = __expf(mrun[r] - mnew[r]);
      mrun[r]  = mnew[r];
    }
    float rs[4] = {0.f, 0.f, 0.f, 0.f};
#pragma unroll
    for (int t = 0; t < 4; ++t)
#pragma unroll
      for (int r = 0; r < 4; ++r) {
        float p = __expf(sv[t][r] - mnew[r]);
        sv[t][r] = p;
        rs[r] += p;
      }
#pragma unroll
    for (int r = 0; r < 4; ++r) {
      float v = rs[r];
#pragma unroll
      for (int off = 1; off < 16; off <<= 1) v += __shfl_xor(v, off);
      lrun[r] = lrun[r]*alpha[r] + v;
    }
#pragma unroll
    for (int t = 0; t < 16; ++t) {
      o[t][0] *= alpha[0]; o[t][1] *= alpha[1];
      o[t][2] *= alpha[2]; o[t][3] *= alpha[3];
    }
    __syncthreads();
#pragma unroll
    for (int t = 0; t < 4; ++t)
#pragma unroll
      for (int r = 0; r < 4; ++r)
        plds[(hi*4 + r)*72 + t*16 + lo] = f2b(sv[t][r]);
    __syncthreads();
    short8 pf0 = *(const short8*)&plds[lo*72 + hi*8];
    short8 pf1 = *(const short8*)&plds[lo*72 + 32 + hi*8];
#pragma unroll
    for (int t = 0; t < 16; ++t) {
      short8 vb0 = ld8(vtb + (size_t)(t*16 + lo)*MPAD + m0 + hi*8);
      o[t] = __builtin_amdgcn_mfma_f32_16x16x32_bf16(pf0, vb0, o[t], 0, 0, 0);
    }
#pragma unroll
    for (int t = 0; t < 16; ++t) {
      short8 vb1 = ld8(vtb + (size_t)(t*16 + lo)*MPAD + m0 + 32 + hi*8);
      o[t] = __builtin_amdgcn_mfma_f32_16x16x32_bf16(pf1, vb1, o[t], 0, 0, 0);
    }
  }
  float inv[4];
#pragma unroll
  for (int r = 0; r < 4; ++r) inv[r] = 1.0f / lrun[r];
  const float* ib = img  + (size_t)b*CC*HWS;
  float*       ob = out0 + (size_t)b*CC*HWS;
#pragma unroll
  for (int t = 0; t < 16; ++t)
#pragma unroll
    for (int r = 0; r < 4; ++r) {
      int d = t*16 + lo, n = n0 + hi*4 + r;
      size_t idx = (size_t)d*HWS + n;
      ob[idx] = o[t][r]*inv[r] + ib[idx];
    }
}

// ---- queries[b][q][d] = sum_c img[b][c][id]*v_w[d][c]  (fp32 seq FMA)
__global__ __launch_bounds__(256) void gather_kernel(const float* __restrict__ img,
    const float* __restrict__ vw, const int* __restrict__ qids, float* __restrict__ out1) {
  int blk = blockIdx.x;
  int b = blk / 150, q = blk % 150;
  int dd = threadIdx.x;
  __shared__ float col[CC];
  int id = qids[b*150 + q];
  col[dd] = img[((size_t)b*CC + dd)*HWS + id];
  __syncthreads();
  const float* vr = vw + dd*CC;
  float acc = 0.f;
  for (int c = 0; c < CC; ++c) acc = fmaf(col[c], vr[c], acc);
  out1[((size_t)(b*150 + q))*CC + dd] = acc;
}

extern "C" void kernel_launch(void* const* d_in, const int* in_sizes, int n_in,
                              void* d_out, int out_size, void* d_ws, size_t ws_size,
                              hipStream_t stream) {
  const float* img  = (const float*)d_in[0];
  const float* exe  = (const float*)d_in[1];
  const float* mask = (const float*)d_in[2];
  const float* sim  = (const float*)d_in[3];
  const float* vw   = (const float*)d_in[4];
  float* out0 = (float*)d_out;
  float* out1 = out0 + (size_t)NB*CC*HWS;

  char* ws = (char*)d_ws;
  size_t o = 0;
  unsigned short* Kt  = (unsigned short*)(ws + o); o += (size_t)NB*MPAD*CC*2;
  unsigned short* Tb  = (unsigned short*)(ws + o); o += (size_t)NB*HWS*CC*2;
  unsigned short* Vbt = (unsigned short*)(ws + o); o += (size_t)NB*CC*MPAD*2;
  unsigned short* St  = (unsigned short*)(ws + o); o += (size_t)CC*CC*2;
  unsigned short* Vw  = (unsigned short*)(ws + o); o += (size_t)CC*CC*2;
  float*          scores = (float*)(ws + o);       o += (size_t)NB*HWS*4;
  int*            qids   = (int*)(ws + o);         o += (size_t)NB*150*4;

  prep_mats  <<<dim3(CC),        dim3(CC),  0, stream>>>(sim, vw, St, Vw);
  build_kt   <<<dim3(NB, 65, 4), dim3(256), 0, stream>>>(img, exe, Kt);
  gemm_small <<<dim3(NB, 64, 4), dim3(256), 0, stream>>>(Kt, St, Tb, nullptr, 0);
  gemm_small <<<dim3(NB, 65, 4), dim3(256), 0, stream>>>(Kt, Vw, nullptr, Vbt, 1);
  scores_kernel<<<dim3(NB, 256), dim3(256), 0, stream>>>(img, sim, exe, scores);
  select_kernel<<<dim3(NB),      dim3(256), 0, stream>>>(scores, qids);
  flash_kernel <<<dim3(1024),    dim3(64),  0, stream>>>(Tb, Kt, Vbt, mask, img, out0);
  gather_kernel<<<dim3(NB*150),  dim3(256), 0, stream>>>(img, vw, qids, out1);
}

// Round 5
// 978.177 us; speedup vs baseline: 1.0764x; 1.0764x over previous
//
#include <hip/hip_runtime.h>

#define CC   256
#define HWS  4096
#define MPAD 4160   // 65*64, rows >= 4097 zero-padded
#define NB   4

typedef __attribute__((ext_vector_type(8))) short   short8;
typedef __attribute__((ext_vector_type(4))) float   floatx4;

static __device__ __forceinline__ short8 ld8(const unsigned short* p) {
  return *(const short8*)p;
}
static __device__ __forceinline__ unsigned short f2b(float x) {
  union { float f; unsigned u; } v; v.f = x;
  unsigned r = v.u + 0x7FFFu + ((v.u >> 16) & 1u);
  return (unsigned short)(r >> 16);
}
static __device__ __forceinline__ float b2f(unsigned short x) {
  union { unsigned u; float f; } v; v.u = ((unsigned)x) << 16;
  return v.f;
}

// ---- St[d][c] = sim[c][d] (bf16), Vw[d][c] = v_w[d][c] (bf16)
__global__ void prep_mats(const float* __restrict__ sim, const float* __restrict__ vw,
                          unsigned short* __restrict__ St, unsigned short* __restrict__ Vw) {
  int dd = blockIdx.x, c = threadIdx.x;
  St[dd*CC + c] = f2b(sim[c*CC + dd]);
  Vw[dd*CC + c] = f2b(vw[dd*CC + c]);
}

// ---- Kt[b][m][d] = bf16(concat[b][d][m]); m==4096 -> 1.2*exe; m>4096 -> 0
__global__ void build_kt(const float* __restrict__ img, const float* __restrict__ exe,
                         unsigned short* __restrict__ Kt) {
  int b = blockIdx.x, mt = blockIdx.y, dt = blockIdx.z;
  int tid = threadIdx.x;
  int m0 = mt*64, d0 = dt*64;
  if (mt == 64) {
    for (int i = 0; i < 16; ++i) {
      int m = m0 + (tid>>6) + i*4;
      int d = d0 + (tid&63);
      unsigned short v = 0;
      if (m == 4096) v = f2b(1.2f * exe[b*CC + d]);
      Kt[((size_t)b*MPAD + m)*CC + d] = v;
    }
    return;
  }
  __shared__ float tile[64][65];
  for (int i = 0; i < 16; ++i) {
    int dl = (tid>>6) + i*4, ml = tid&63;
    tile[dl][ml] = img[((size_t)b*CC + d0+dl)*HWS + m0+ml];
  }
  __syncthreads();
  for (int i = 0; i < 16; ++i) {
    int ml = (tid>>6) + i*4, dl = tid&63;
    Kt[((size_t)b*MPAD + m0+ml)*CC + d0+dl] = f2b(tile[dl][ml]);
  }
}

// ---- mode 0: T[b][n][d] = bf16( sum_c Kt[n][c]*St[d][c] )           (rows < HWS)
// ---- mode 1: Vbt[b][d][m] = bf16( sum_c Kt[m][c]*Vw[d][c] )         (rows < MPAD)
__global__ __launch_bounds__(256) void gemm_small(const unsigned short* __restrict__ Kt,
    const unsigned short* __restrict__ Bm, unsigned short* __restrict__ Tout,
    unsigned short* __restrict__ Vbt, int mode) {
  int b  = blockIdx.x;
  int r0 = blockIdx.y*64 + (threadIdx.x>>6)*16;
  int c0 = blockIdx.z*64;
  int lane = threadIdx.x & 63;
  int lo = lane & 15, hi = lane >> 4;
  floatx4 acc[4] = {};
  const unsigned short* arow = Kt + ((size_t)b*MPAD + r0 + lo)*CC + hi*8;
#pragma unroll
  for (int k = 0; k < 8; ++k) {
    short8 af = ld8(arow + k*32);
#pragma unroll
    for (int t = 0; t < 4; ++t) {
      short8 bf = ld8(Bm + (size_t)(c0 + t*16 + lo)*CC + k*32 + hi*8);
      acc[t] = __builtin_amdgcn_mfma_f32_16x16x32_bf16(af, bf, acc[t], 0, 0, 0);
    }
  }
  if (mode == 0) {
#pragma unroll
    for (int t = 0; t < 4; ++t)
#pragma unroll
      for (int r = 0; r < 4; ++r) {
        int n = r0 + hi*4 + r, dd = c0 + t*16 + lo;
        Tout[((size_t)b*HWS + n)*CC + dd] = f2b(acc[t][r]);
      }
  } else {
#pragma unroll
    for (int t = 0; t < 4; ++t)
#pragma unroll
      for (int r = 0; r < 4; ++r) {
        int m = r0 + hi*4 + r, dd = c0 + t*16 + lo;
        Vbt[((size_t)b*CC + dd)*MPAD + m] = f2b(acc[t][r]);
      }
  }
}

// ---- score mimicry of np/BLAS fp32 T-path, sequential FMA everywhere
__global__ __launch_bounds__(256) void scores_kernel(const float* __restrict__ img,
    const float* __restrict__ sim, const float* __restrict__ exe,
    float* __restrict__ score32) {
  int b = blockIdx.x, n0 = blockIdx.y*16;
  int d = threadIdx.x;
  __shared__ float U[16][257];        // U[nl][c] = img[b, c, n0+nl]
  __shared__ float R[16][256];        // T32[nl][d]
  __shared__ float E[256];
  for (int idx = threadIdx.x; idx < 16*256; idx += 256) {
    int nl = idx & 15, c = idx >> 4;
    U[nl][c] = img[((size_t)b*CC + c)*HWS + n0 + nl];
  }
  E[d] = 1.2f * exe[b*CC + d];
  __syncthreads();
  float acc[16];
#pragma unroll
  for (int nl = 0; nl < 16; ++nl) acc[nl] = 0.f;
  for (int c = 0; c < CC; ++c) {
    float s_cd = sim[c*CC + d];
#pragma unroll
    for (int nl = 0; nl < 16; ++nl) acc[nl] = fmaf(U[nl][c], s_cd, acc[nl]);
  }
#pragma unroll
  for (int nl = 0; nl < 16; ++nl) R[nl][d] = acc[nl];
  __syncthreads();
  if (d < 16) {
    float s = 0.f;
    for (int dd = 0; dd < CC; ++dd) s = fmaf(R[d][dd], E[dd], s);
    score32[b*HWS + n0 + d] = s;
  }
}

// ---- local-max penalty + iterative top-150, register-cached local best
__global__ __launch_bounds__(256) void select_kernel(const float* __restrict__ scores,
                                                     int* __restrict__ qids) {
  int b = blockIdx.x, tid = threadIdx.x;
  __shared__ float sc[HWS];
  __shared__ float rv[4];
  __shared__ int   ri[4];
  __shared__ int   winner;
  for (int i = 0; i < 16; ++i) sc[tid + i*256] = scores[b*HWS + tid + i*256];
  __syncthreads();
  float pv[16];
  for (int i = 0; i < 16; ++i) {
    int idx = tid + i*256;
    int y = idx >> 6, x = idx & 63;
    float c0 = sc[idx];
    float v = c0;
    if (y >= 1 && y <= 62 && x >= 1 && x <= 62) {
      bool ismax = (c0 > sc[idx-64]) && (c0 >= sc[idx+64]) &&
                   (c0 > sc[idx-1])  && (c0 >= sc[idx+1]);
      if (!ismax) v = c0 - 1e9f;     // fp32, as reference (simil - NEG)
    }
    pv[i] = v;
  }
  // local best (ascending slot order -> smallest index wins ties)
  float bv = -3.0e38f; int bi = 0x7fffffff;
  for (int i = 0; i < 16; ++i) {
    if (pv[i] > bv) { bv = pv[i]; bi = tid + i*256; }
  }
  for (int q = 0; q < 150; ++q) {
    float wv = bv; int wi = bi;
#pragma unroll
    for (int off = 32; off >= 1; off >>= 1) {
      float ov = __shfl_xor(wv, off);
      int   oi = __shfl_xor(wi, off);
      if (ov > wv || (ov == wv && oi < wi)) { wv = ov; wi = oi; }
    }
    if ((tid & 63) == 0) { rv[tid>>6] = wv; ri[tid>>6] = wi; }
    __syncthreads();
    if (tid == 0) {
      float bb = rv[0]; int ii = ri[0];
      for (int w2 = 1; w2 < 4; ++w2)
        if (rv[w2] > bb || (rv[w2] == bb && ri[w2] < ii)) { bb = rv[w2]; ii = ri[w2]; }
      qids[b*150 + q] = ii;
      winner = ii;
    }
    __syncthreads();
    int wn = winner;
    if ((wn & 255) == tid) {
      pv[wn >> 8] = -3.0e38f;
      bv = -3.0e38f; bi = 0x7fffffff;
      for (int i = 0; i < 16; ++i) {
        if (pv[i] > bv) { bv = pv[i]; bi = tid + i*256; }
      }
    }
  }
}

// ---- fused flash attention: 4 waves/block, each wave a private m-slice of the
//      same 16 Q-rows; in-LDS combine of (o, m, l) partials at block end.
//      No per-tile barriers: each wave's P-transform buffer is private.
__global__ __launch_bounds__(256, 4) void flash_kernel(
    const unsigned short* __restrict__ Tb, const unsigned short* __restrict__ Kt,
    const unsigned short* __restrict__ Vbt, const float* __restrict__ mask,
    const float* __restrict__ img, float* __restrict__ out0) {
  int blk = blockIdx.x;
  int b = blk >> 8;
  int n0 = (blk & 255) << 4;
  int tid  = threadIdx.x;
  int wave = tid >> 6;
  int lane = tid & 63;
  int lo = lane & 15, hi = lane >> 4;

  __shared__ unsigned short obf[4][16][264];  // bf16 o-partials; also hosts per-wave P buffer
  __shared__ float mlm[4][16], mll[4][16];
  unsigned short* plw = &obf[wave][0][0];     // private 16x72 P-transform region

  // Q fragments: rows n0+lo (same for all waves), 8 k-steps of 32
  short8 q[8];
  const unsigned short* tb = Tb + ((size_t)b*HWS + n0 + lo)*CC + hi*8;
#pragma unroll
  for (int k = 0; k < 8; ++k) q[k] = ld8(tb + k*32);

  const float* mk = mask + b*HWS;
  float qmr[4];
#pragma unroll
  for (int r = 0; r < 4; ++r) qmr[r] = mk[n0 + hi*4 + r];

  float mrun[4], lrun[4];
#pragma unroll
  for (int r = 0; r < 4; ++r) { mrun[r] = -1e30f; lrun[r] = 0.f; }
  floatx4 o[16] = {};

  const unsigned short* ktb = Kt  + (size_t)b*MPAD*CC;
  const unsigned short* vtb = Vbt + (size_t)b*CC*MPAD;

  int mtBeg = wave*16;
  int mtEnd = (wave == 3) ? 65 : mtBeg + 16;
  for (int mt = mtBeg; mt < mtEnd; ++mt) {
    int m0 = mt*64;
    floatx4 s[4] = {};
#pragma unroll
    for (int k = 0; k < 8; ++k) {
#pragma unroll
      for (int t = 0; t < 4; ++t) {
        short8 kb = ld8(ktb + (size_t)(m0 + t*16 + lo)*CC + k*32 + hi*8);
        s[t] = __builtin_amdgcn_mfma_f32_16x16x32_bf16(q[k], kb, s[t], 0, 0, 0);
      }
    }
    // mask + online softmax
    float sv[4][4];
#pragma unroll
    for (int t = 0; t < 4; ++t) {
      int m = m0 + t*16 + lo;
      float km = (m < HWS) ? mk[m] : 1.0f;
      bool pad = (m > HWS);              // m==4096 is exe column (never masked)
#pragma unroll
      for (int r = 0; r < 4; ++r) {
        float v = s[t][r];
        if (m < HWS && qmr[r]*km != 1.0f) v -= 1e9f;
        if (pad) v = -3.0e38f;
        sv[t][r] = v;
      }
    }
    float mnew[4], alpha[4];
#pragma unroll
    for (int r = 0; r < 4; ++r) {
      float v = fmaxf(fmaxf(sv[0][r], sv[1][r]), fmaxf(sv[2][r], sv[3][r]));
#pragma unroll
      for (int off = 1; off < 16; off <<= 1) v = fmaxf(v, __shfl_xor(v, off));
      mnew[r]  = fmaxf(mrun[r], v);
      alpha[r] = __expf(mrun[r] - mnew[r]);
      mrun[r]  = mnew[r];
    }
    float rs[4] = {0.f, 0.f, 0.f, 0.f};
#pragma unroll
    for (int t = 0; t < 4; ++t)
#pragma unroll
      for (int r = 0; r < 4; ++r) {
        float p = __expf(sv[t][r] - mnew[r]);
        sv[t][r] = p;
        rs[r] += p;
      }
#pragma unroll
    for (int r = 0; r < 4; ++r) {
      float v = rs[r];
#pragma unroll
      for (int off = 1; off < 16; off <<= 1) v += __shfl_xor(v, off);
      lrun[r] = lrun[r]*alpha[r] + v;
    }
#pragma unroll
    for (int t = 0; t < 16; ++t) {
      o[t][0] *= alpha[0]; o[t][1] *= alpha[1];
      o[t][2] *= alpha[2]; o[t][3] *= alpha[3];
    }
    // P: C-layout -> A-layout via private LDS region (intra-wave ordering only)
#pragma unroll
    for (int t = 0; t < 4; ++t)
#pragma unroll
      for (int r = 0; r < 4; ++r)
        plw[(hi*4 + r)*72 + t*16 + lo] = f2b(sv[t][r]);
    short8 pf0 = *(const short8*)&plw[lo*72 + hi*8];
    short8 pf1 = *(const short8*)&plw[lo*72 + 32 + hi*8];
    // PV
#pragma unroll
    for (int t = 0; t < 16; ++t) {
      short8 vb0 = ld8(vtb + (size_t)(t*16 + lo)*MPAD + m0 + hi*8);
      o[t] = __builtin_amdgcn_mfma_f32_16x16x32_bf16(pf0, vb0, o[t], 0, 0, 0);
    }
#pragma unroll
    for (int t = 0; t < 16; ++t) {
      short8 vb1 = ld8(vtb + (size_t)(t*16 + lo)*MPAD + m0 + 32 + hi*8);
      o[t] = __builtin_amdgcn_mfma_f32_16x16x32_bf16(pf1, vb1, o[t], 0, 0, 0);
    }
  }
  // write per-wave partials (unnormalized o in bf16; m, l per row)
#pragma unroll
  for (int t = 0; t < 16; ++t)
#pragma unroll
    for (int r = 0; r < 4; ++r)
      obf[wave][hi*4 + r][t*16 + lo] = f2b(o[t][r]);
  if (lo == 0) {
#pragma unroll
    for (int r = 0; r < 4; ++r) {
      mlm[wave][hi*4 + r] = mrun[r];
      mll[wave][hi*4 + r] = lrun[r];
    }
  }
  __syncthreads();
  // combine: thread -> (n = n0 + (tid&15), d = (tid>>4) + 16*j)
  int nl = tid & 15, dg = tid >> 4;
  float sw[4];
  float M = -3.0e38f;
#pragma unroll
  for (int w = 0; w < 4; ++w) M = fmaxf(M, mlm[w][nl]);
  float L = 0.f;
#pragma unroll
  for (int w = 0; w < 4; ++w) { sw[w] = __expf(mlm[w][nl] - M); L += mll[w][nl]*sw[w]; }
  float invL = 1.0f / L;
  const float* ib = img  + (size_t)b*CC*HWS + n0 + nl;
  float*       ob = out0 + (size_t)b*CC*HWS + n0 + nl;
#pragma unroll
  for (int j = 0; j < 16; ++j) {
    int d = dg + j*16;
    float acc = 0.f;
#pragma unroll
    for (int w = 0; w < 4; ++w) acc += b2f(obf[w][nl][d]) * sw[w];
    ob[(size_t)d*HWS] = acc*invL + ib[(size_t)d*HWS];
  }
}

// ---- queries[b][q][d] = sum_c img[b][c][id]*v_w[d][c]  (fp32 seq FMA)
__global__ __launch_bounds__(256) void gather_kernel(const float* __restrict__ img,
    const float* __restrict__ vw, const int* __restrict__ qids, float* __restrict__ out1) {
  int blk = blockIdx.x;
  int b = blk / 150, q = blk % 150;
  int dd = threadIdx.x;
  __shared__ float col[CC];
  int id = qids[b*150 + q];
  col[dd] = img[((size_t)b*CC + dd)*HWS + id];
  __syncthreads();
  const float* vr = vw + dd*CC;
  float acc = 0.f;
  for (int c = 0; c < CC; ++c) acc = fmaf(col[c], vr[c], acc);
  out1[((size_t)(b*150 + q))*CC + dd] = acc;
}

extern "C" void kernel_launch(void* const* d_in, const int* in_sizes, int n_in,
                              void* d_out, int out_size, void* d_ws, size_t ws_size,
                              hipStream_t stream) {
  const float* img  = (const float*)d_in[0];
  const float* exe  = (const float*)d_in[1];
  const float* mask = (const float*)d_in[2];
  const float* sim  = (const float*)d_in[3];
  const float* vw   = (const float*)d_in[4];
  float* out0 = (float*)d_out;
  float* out1 = out0 + (size_t)NB*CC*HWS;

  char* ws = (char*)d_ws;
  size_t o = 0;
  unsigned short* Kt  = (unsigned short*)(ws + o); o += (size_t)NB*MPAD*CC*2;
  unsigned short* Tb  = (unsigned short*)(ws + o); o += (size_t)NB*HWS*CC*2;
  unsigned short* Vbt = (unsigned short*)(ws + o); o += (size_t)NB*CC*MPAD*2;
  unsigned short* St  = (unsigned short*)(ws + o); o += (size_t)CC*CC*2;
  unsigned short* Vw  = (unsigned short*)(ws + o); o += (size_t)CC*CC*2;
  float*          scores = (float*)(ws + o);       o += (size_t)NB*HWS*4;
  int*            qids   = (int*)(ws + o);         o += (size_t)NB*150*4;

  prep_mats  <<<dim3(CC),        dim3(CC),  0, stream>>>(sim, vw, St, Vw);
  build_kt   <<<dim3(NB, 65, 4), dim3(256), 0, stream>>>(img, exe, Kt);
  gemm_small <<<dim3(NB, 64, 4), dim3(256), 0, stream>>>(Kt, St, Tb, nullptr, 0);
  gemm_small <<<dim3(NB, 65, 4), dim3(256), 0, stream>>>(Kt, Vw, nullptr, Vbt, 1);
  scores_kernel<<<dim3(NB, 256), dim3(256), 0, stream>>>(img, sim, exe, scores);
  select_kernel<<<dim3(NB),      dim3(256), 0, stream>>>(scores, qids);
  flash_kernel <<<dim3(1024),    dim3(256), 0, stream>>>(Tb, Kt, Vbt, mask, img, out0);
  gather_kernel<<<dim3(NB*150),  dim3(256), 0, stream>>>(img, vw, qids, out1);
}

// Round 6
// 722.487 us; speedup vs baseline: 1.4573x; 1.3539x over previous
//
#include <hip/hip_runtime.h>

#define CC   256
#define HWS  4096
#define MPAD 4160   // 65*64, rows >= 4097 zero-padded
#define NB   4
#define NTIL 65

typedef __attribute__((ext_vector_type(8))) short   short8;
typedef __attribute__((ext_vector_type(4))) float   floatx4;

static __device__ __forceinline__ short8 ld8(const unsigned short* p) {
  return *(const short8*)p;
}
static __device__ __forceinline__ void st8(unsigned short* p, short8 v) {
  *(short8*)p = v;
}
static __device__ __forceinline__ unsigned short f2b(float x) {
  union { float f; unsigned u; } v; v.f = x;
  unsigned r = v.u + 0x7FFFu + ((v.u >> 16) & 1u);
  return (unsigned short)(r >> 16);
}
static __device__ __forceinline__ float b2f(unsigned short x) {
  union { unsigned u; float f; } v; v.u = ((unsigned)x) << 16;
  return v.f;
}

// ---- St[d][c] = sim[c][d] (bf16), Vw[d][c] = v_w[d][c] (bf16)
__global__ void prep_mats(const float* __restrict__ sim, const float* __restrict__ vw,
                          unsigned short* __restrict__ St, unsigned short* __restrict__ Vw) {
  int dd = blockIdx.x, c = threadIdx.x;
  St[dd*CC + c] = f2b(sim[c*CC + dd]);
  Vw[dd*CC + c] = f2b(vw[dd*CC + c]);
}

// ---- Kt[b][m][d] = bf16(concat[b][d][m]); m==4096 -> 1.2*exe; m>4096 -> 0
__global__ void build_kt(const float* __restrict__ img, const float* __restrict__ exe,
                         unsigned short* __restrict__ Kt) {
  int b = blockIdx.x, mt = blockIdx.y, dt = blockIdx.z;
  int tid = threadIdx.x;
  int m0 = mt*64, d0 = dt*64;
  if (mt == 64) {
    for (int i = 0; i < 16; ++i) {
      int m = m0 + (tid>>6) + i*4;
      int d = d0 + (tid&63);
      unsigned short v = 0;
      if (m == 4096) v = f2b(1.2f * exe[b*CC + d]);
      Kt[((size_t)b*MPAD + m)*CC + d] = v;
    }
    return;
  }
  __shared__ float tile[64][65];
  for (int i = 0; i < 16; ++i) {
    int dl = (tid>>6) + i*4, ml = tid&63;
    tile[dl][ml] = img[((size_t)b*CC + d0+dl)*HWS + m0+ml];
  }
  __syncthreads();
  for (int i = 0; i < 16; ++i) {
    int ml = (tid>>6) + i*4, dl = tid&63;
    Kt[((size_t)b*MPAD + m0+ml)*CC + d0+dl] = f2b(tile[dl][ml]);
  }
}

// ---- mode 0: T[b][n][d] = bf16( sum_c Kt[n][c]*St[d][c] )           (rows < HWS)
// ---- mode 1: Vbt[b][d][m] = bf16( sum_c Kt[m][c]*Vw[d][c] )         (rows < MPAD)
__global__ __launch_bounds__(256) void gemm_small(const unsigned short* __restrict__ Kt,
    const unsigned short* __restrict__ Bm, unsigned short* __restrict__ Tout,
    unsigned short* __restrict__ Vbt, int mode) {
  int b  = blockIdx.x;
  int r0 = blockIdx.y*64 + (threadIdx.x>>6)*16;
  int c0 = blockIdx.z*64;
  int lane = threadIdx.x & 63;
  int lo = lane & 15, hi = lane >> 4;
  floatx4 acc[4] = {};
  const unsigned short* arow = Kt + ((size_t)b*MPAD + r0 + lo)*CC + hi*8;
#pragma unroll
  for (int k = 0; k < 8; ++k) {
    short8 af = ld8(arow + k*32);
#pragma unroll
    for (int t = 0; t < 4; ++t) {
      short8 bf = ld8(Bm + (size_t)(c0 + t*16 + lo)*CC + k*32 + hi*8);
      acc[t] = __builtin_amdgcn_mfma_f32_16x16x32_bf16(af, bf, acc[t], 0, 0, 0);
    }
  }
  if (mode == 0) {
#pragma unroll
    for (int t = 0; t < 4; ++t)
#pragma unroll
      for (int r = 0; r < 4; ++r) {
        int n = r0 + hi*4 + r, dd = c0 + t*16 + lo;
        Tout[((size_t)b*HWS + n)*CC + dd] = f2b(acc[t][r]);
      }
  } else {
#pragma unroll
    for (int t = 0; t < 4; ++t)
#pragma unroll
      for (int r = 0; r < 4; ++r) {
        int m = r0 + hi*4 + r, dd = c0 + t*16 + lo;
        Vbt[((size_t)b*CC + dd)*MPAD + m] = f2b(acc[t][r]);
      }
  }
}

// ---- reorder K and V into MFMA-fragment-major order, 1KB per instruction slot.
//  Kf[b][mt][s=k*4+t][lane][8] = Kt[b][m0+t*16+lo][k*32+hi*8+e]
//  Vf[b][mt][s=h*16+t][lane][8] = Vbt[b][t*16+lo][m0+h*32+hi*8+e]
// grid (NB, NTIL), block 256
__global__ __launch_bounds__(256) void reorder_kv(const unsigned short* __restrict__ Kt,
    const unsigned short* __restrict__ Vbt, unsigned short* __restrict__ Kf,
    unsigned short* __restrict__ Vf) {
  int b = blockIdx.x, mt = blockIdx.y;
  int m0 = mt*64;
  int tid = threadIdx.x;
  int w = tid >> 6, lane = tid & 63;
  int lo = lane & 15, hi = lane >> 4;
  size_t tile = (size_t)(b*NTIL + mt)*16384;
  unsigned short* kf = Kf + tile;
  unsigned short* vf = Vf + tile;
  const unsigned short* ktb = Kt  + (size_t)b*MPAD*CC;
  const unsigned short* vtb = Vbt + (size_t)b*CC*MPAD;
#pragma unroll
  for (int i = 0; i < 8; ++i) {
    int s = i*4 + w;
    { // K slot
      int k = s >> 2, t = s & 3;
      short8 v = ld8(ktb + (size_t)(m0 + t*16 + lo)*CC + k*32 + hi*8);
      st8(kf + s*512 + lane*8, v);
    }
    { // V slot
      int h = s >> 4, t = s & 15;
      short8 v = ld8(vtb + (size_t)(t*16 + lo)*MPAD + m0 + h*32 + hi*8);
      st8(vf + s*512 + lane*8, v);
    }
  }
}

// ---- score mimicry of np/BLAS fp32 T-path, sequential FMA everywhere
__global__ __launch_bounds__(256) void scores_kernel(const float* __restrict__ img,
    const float* __restrict__ sim, const float* __restrict__ exe,
    float* __restrict__ score32) {
  int b = blockIdx.x, n0 = blockIdx.y*16;
  int d = threadIdx.x;
  __shared__ float U[16][257];        // U[nl][c] = img[b, c, n0+nl]
  __shared__ float R[16][256];        // T32[nl][d]
  __shared__ float E[256];
  for (int idx = threadIdx.x; idx < 16*256; idx += 256) {
    int nl = idx & 15, c = idx >> 4;
    U[nl][c] = img[((size_t)b*CC + c)*HWS + n0 + nl];
  }
  E[d] = 1.2f * exe[b*CC + d];
  __syncthreads();
  float acc[16];
#pragma unroll
  for (int nl = 0; nl < 16; ++nl) acc[nl] = 0.f;
  for (int c = 0; c < CC; ++c) {
    float s_cd = sim[c*CC + d];
#pragma unroll
    for (int nl = 0; nl < 16; ++nl) acc[nl] = fmaf(U[nl][c], s_cd, acc[nl]);
  }
#pragma unroll
  for (int nl = 0; nl < 16; ++nl) R[nl][d] = acc[nl];
  __syncthreads();
  if (d < 16) {
    float s = 0.f;
    for (int dd = 0; dd < CC; ++dd) s = fmaf(R[d][dd], E[dd], s);
    score32[b*HWS + n0 + d] = s;
  }
}

// ---- local-max penalty + iterative top-150, register-cached local best
__global__ __launch_bounds__(256) void select_kernel(const float* __restrict__ scores,
                                                     int* __restrict__ qids) {
  int b = blockIdx.x, tid = threadIdx.x;
  __shared__ float sc[HWS];
  __shared__ float rv[4];
  __shared__ int   ri[4];
  __shared__ int   winner;
  for (int i = 0; i < 16; ++i) sc[tid + i*256] = scores[b*HWS + tid + i*256];
  __syncthreads();
  float pv[16];
  for (int i = 0; i < 16; ++i) {
    int idx = tid + i*256;
    int y = idx >> 6, x = idx & 63;
    float c0 = sc[idx];
    float v = c0;
    if (y >= 1 && y <= 62 && x >= 1 && x <= 62) {
      bool ismax = (c0 > sc[idx-64]) && (c0 >= sc[idx+64]) &&
                   (c0 > sc[idx-1])  && (c0 >= sc[idx+1]);
      if (!ismax) v = c0 - 1e9f;     // fp32, as reference (simil - NEG)
    }
    pv[i] = v;
  }
  float bv = -3.0e38f; int bi = 0x7fffffff;
  for (int i = 0; i < 16; ++i) {
    if (pv[i] > bv) { bv = pv[i]; bi = tid + i*256; }
  }
  for (int q = 0; q < 150; ++q) {
    float wv = bv; int wi = bi;
#pragma unroll
    for (int off = 32; off >= 1; off >>= 1) {
      float ov = __shfl_xor(wv, off);
      int   oi = __shfl_xor(wi, off);
      if (ov > wv || (ov == wv && oi < wi)) { wv = ov; wi = oi; }
    }
    if ((tid & 63) == 0) { rv[tid>>6] = wv; ri[tid>>6] = wi; }
    __syncthreads();
    if (tid == 0) {
      float bb = rv[0]; int ii = ri[0];
      for (int w2 = 1; w2 < 4; ++w2)
        if (rv[w2] > bb || (rv[w2] == bb && ri[w2] < ii)) { bb = rv[w2]; ii = ri[w2]; }
      qids[b*150 + q] = ii;
      winner = ii;
    }
    __syncthreads();
    int wn = winner;
    if ((wn & 255) == tid) {
      pv[wn >> 8] = -3.0e38f;
      bv = -3.0e38f; bi = 0x7fffffff;
      for (int i = 0; i < 16; ++i) {
        if (pv[i] > bv) { bv = pv[i]; bi = tid + i*256; }
      }
    }
  }
}

// ---- fused flash attention: 4 waves/block, private m-slices, fragment-major
//      fully-coalesced K/V streams, in-LDS combine at block end.
__global__ __launch_bounds__(256, 4) void flash_kernel(
    const unsigned short* __restrict__ Tb, const unsigned short* __restrict__ Kf,
    const unsigned short* __restrict__ Vf, const float* __restrict__ mask,
    const float* __restrict__ img, float* __restrict__ out0) {
  int blk = blockIdx.x;
  // XCD-aware swizzle: batch b pinned to XCD pair {2b, 2b+1} (blocks dispatch
  // round-robin over 8 XCDs); n-index reconstructed bijectively.
  int b  = (blk & 7) >> 1;
  int n0 = (((blk >> 3) << 1) | (blk & 1)) << 4;
  int tid  = threadIdx.x;
  int wave = tid >> 6;
  int lane = tid & 63;
  int lo = lane & 15, hi = lane >> 4;

  __shared__ unsigned short obf[4][16][264];  // bf16 o-partials; also hosts per-wave P buffer
  __shared__ float mlm[4][16], mll[4][16];
  unsigned short* plw = &obf[wave][0][0];     // private 16x72 P-transform region

  // Q fragments: rows n0+lo (same for all waves), 8 k-steps of 32
  short8 q[8];
  const unsigned short* tb = Tb + ((size_t)b*HWS + n0 + lo)*CC + hi*8;
#pragma unroll
  for (int k = 0; k < 8; ++k) q[k] = ld8(tb + k*32);

  const float* mk = mask + b*HWS;
  float qmr[4];
#pragma unroll
  for (int r = 0; r < 4; ++r) qmr[r] = mk[n0 + hi*4 + r];

  float mrun[4], lrun[4];
#pragma unroll
  for (int r = 0; r < 4; ++r) { mrun[r] = -1e30f; lrun[r] = 0.f; }
  floatx4 o[16] = {};

  int mtBeg = wave*16;
  int mtEnd = (wave == 3) ? NTIL : mtBeg + 16;
  for (int mt = mtBeg; mt < mtEnd; ++mt) {
    int m0 = mt*64;
    const unsigned short* kf = Kf + (size_t)(b*NTIL + mt)*16384 + lane*8;
    const unsigned short* vf = Vf + (size_t)(b*NTIL + mt)*16384 + lane*8;
    floatx4 s[4] = {};
#pragma unroll
    for (int k = 0; k < 8; ++k) {
#pragma unroll
      for (int t = 0; t < 4; ++t) {
        short8 kb = ld8(kf + (k*4 + t)*512);
        s[t] = __builtin_amdgcn_mfma_f32_16x16x32_bf16(q[k], kb, s[t], 0, 0, 0);
      }
    }
    // mask + online softmax
    float sv[4][4];
#pragma unroll
    for (int t = 0; t < 4; ++t) {
      int m = m0 + t*16 + lo;
      float km = (m < HWS) ? mk[m] : 1.0f;
      bool pad = (m > HWS);              // m==4096 is exe column (never masked)
#pragma unroll
      for (int r = 0; r < 4; ++r) {
        float v = s[t][r];
        if (m < HWS && qmr[r]*km != 1.0f) v -= 1e9f;
        if (pad) v = -3.0e38f;
        sv[t][r] = v;
      }
    }
    float mnew[4], alpha[4];
#pragma unroll
    for (int r = 0; r < 4; ++r) {
      float v = fmaxf(fmaxf(sv[0][r], sv[1][r]), fmaxf(sv[2][r], sv[3][r]));
#pragma unroll
      for (int off = 1; off < 16; off <<= 1) v = fmaxf(v, __shfl_xor(v, off));
      mnew[r]  = fmaxf(mrun[r], v);
      alpha[r] = __expf(mrun[r] - mnew[r]);
      mrun[r]  = mnew[r];
    }
    float rs[4] = {0.f, 0.f, 0.f, 0.f};
#pragma unroll
    for (int t = 0; t < 4; ++t)
#pragma unroll
      for (int r = 0; r < 4; ++r) {
        float p = __expf(sv[t][r] - mnew[r]);
        sv[t][r] = p;
        rs[r] += p;
      }
#pragma unroll
    for (int r = 0; r < 4; ++r) {
      float v = rs[r];
#pragma unroll
      for (int off = 1; off < 16; off <<= 1) v += __shfl_xor(v, off);
      lrun[r] = lrun[r]*alpha[r] + v;
    }
#pragma unroll
    for (int t = 0; t < 16; ++t) {
      o[t][0] *= alpha[0]; o[t][1] *= alpha[1];
      o[t][2] *= alpha[2]; o[t][3] *= alpha[3];
    }
    // P: C-layout -> A-layout via private LDS region (intra-wave ordering only)
#pragma unroll
    for (int t = 0; t < 4; ++t)
#pragma unroll
      for (int r = 0; r < 4; ++r)
        plw[(hi*4 + r)*72 + t*16 + lo] = f2b(sv[t][r]);
    short8 pf0 = *(const short8*)&plw[lo*72 + hi*8];
    short8 pf1 = *(const short8*)&plw[lo*72 + 32 + hi*8];
    // PV (fragment-major V stream)
#pragma unroll
    for (int t = 0; t < 16; ++t) {
      short8 vb0 = ld8(vf + t*512);
      o[t] = __builtin_amdgcn_mfma_f32_16x16x32_bf16(pf0, vb0, o[t], 0, 0, 0);
    }
#pragma unroll
    for (int t = 0; t < 16; ++t) {
      short8 vb1 = ld8(vf + (16 + t)*512);
      o[t] = __builtin_amdgcn_mfma_f32_16x16x32_bf16(pf1, vb1, o[t], 0, 0, 0);
    }
  }
  // write per-wave partials (unnormalized o in bf16; m, l per row)
#pragma unroll
  for (int t = 0; t < 16; ++t)
#pragma unroll
    for (int r = 0; r < 4; ++r)
      obf[wave][hi*4 + r][t*16 + lo] = f2b(o[t][r]);
  if (lo == 0) {
#pragma unroll
    for (int r = 0; r < 4; ++r) {
      mlm[wave][hi*4 + r] = mrun[r];
      mll[wave][hi*4 + r] = lrun[r];
    }
  }
  __syncthreads();
  // combine: thread -> (n = n0 + (tid&15), d = (tid>>4) + 16*j)
  int nl = tid & 15, dg = tid >> 4;
  float sw[4];
  float M = -3.0e38f;
#pragma unroll
  for (int w = 0; w < 4; ++w) M = fmaxf(M, mlm[w][nl]);
  float L = 0.f;
#pragma unroll
  for (int w = 0; w < 4; ++w) { sw[w] = __expf(mlm[w][nl] - M); L += mll[w][nl]*sw[w]; }
  float invL = 1.0f / L;
  const float* ib = img  + (size_t)b*CC*HWS + n0 + nl;
  float*       ob = out0 + (size_t)b*CC*HWS + n0 + nl;
#pragma unroll
  for (int j = 0; j < 16; ++j) {
    int d = dg + j*16;
    float acc = 0.f;
#pragma unroll
    for (int w = 0; w < 4; ++w) acc += b2f(obf[w][nl][d]) * sw[w];
    ob[(size_t)d*HWS] = acc*invL + ib[(size_t)d*HWS];
  }
}

// ---- queries[b][q][d] = sum_c img[b][c][id]*v_w[d][c]  (fp32 seq FMA)
__global__ __launch_bounds__(256) void gather_kernel(const float* __restrict__ img,
    const float* __restrict__ vw, const int* __restrict__ qids, float* __restrict__ out1) {
  int blk = blockIdx.x;
  int b = blk / 150, q = blk % 150;
  int dd = threadIdx.x;
  __shared__ float col[CC];
  int id = qids[b*150 + q];
  col[dd] = img[((size_t)b*CC + dd)*HWS + id];
  __syncthreads();
  const float* vr = vw + dd*CC;
  float acc = 0.f;
  for (int c = 0; c < CC; ++c) acc = fmaf(col[c], vr[c], acc);
  out1[((size_t)(b*150 + q))*CC + dd] = acc;
}

extern "C" void kernel_launch(void* const* d_in, const int* in_sizes, int n_in,
                              void* d_out, int out_size, void* d_ws, size_t ws_size,
                              hipStream_t stream) {
  const float* img  = (const float*)d_in[0];
  const float* exe  = (const float*)d_in[1];
  const float* mask = (const float*)d_in[2];
  const float* sim  = (const float*)d_in[3];
  const float* vw   = (const float*)d_in[4];
  float* out0 = (float*)d_out;
  float* out1 = out0 + (size_t)NB*CC*HWS;

  char* ws = (char*)d_ws;
  size_t o = 0;
  unsigned short* Kt  = (unsigned short*)(ws + o); o += (size_t)NB*MPAD*CC*2;
  unsigned short* Tb  = (unsigned short*)(ws + o); o += (size_t)NB*HWS*CC*2;
  unsigned short* Vbt = (unsigned short*)(ws + o); o += (size_t)NB*CC*MPAD*2;
  unsigned short* Kf  = (unsigned short*)(ws + o); o += (size_t)NB*NTIL*16384*2;
  unsigned short* Vf  = (unsigned short*)(ws + o); o += (size_t)NB*NTIL*16384*2;
  unsigned short* St  = (unsigned short*)(ws + o); o += (size_t)CC*CC*2;
  unsigned short* Vw  = (unsigned short*)(ws + o); o += (size_t)CC*CC*2;
  float*          scores = (float*)(ws + o);       o += (size_t)NB*HWS*4;
  int*            qids   = (int*)(ws + o);         o += (size_t)NB*150*4;

  prep_mats  <<<dim3(CC),         dim3(CC),  0, stream>>>(sim, vw, St, Vw);
  build_kt   <<<dim3(NB, 65, 4),  dim3(256), 0, stream>>>(img, exe, Kt);
  gemm_small <<<dim3(NB, 64, 4),  dim3(256), 0, stream>>>(Kt, St, Tb, nullptr, 0);
  gemm_small <<<dim3(NB, 65, 4),  dim3(256), 0, stream>>>(Kt, Vw, nullptr, Vbt, 1);
  reorder_kv <<<dim3(NB, NTIL),   dim3(256), 0, stream>>>(Kt, Vbt, Kf, Vf);
  scores_kernel<<<dim3(NB, 256),  dim3(256), 0, stream>>>(img, sim, exe, scores);
  select_kernel<<<dim3(NB),       dim3(256), 0, stream>>>(scores, qids);
  flash_kernel <<<dim3(1024),     dim3(256), 0, stream>>>(Tb, Kf, Vf, mask, img, out0);
  gather_kernel<<<dim3(NB*150),   dim3(256), 0, stream>>>(img, vw, qids, out1);
}